// Round 16
// baseline (374.929 us; speedup 1.0000x reference)
//
#include <hip/hip_runtime.h>
#include <math.h>

#define B_   64
#define MD   1024
#define H_   16
#define D_   64
#define LNEPS 1e-5f

// ---------------------------------------------------------------------------
// v15: champion (R11) + k_scores staging rebuilt on global_load_lds (direct
// HBM->LDS DMA, zero ds_writes, zero staging registers) with counted
// s_waitcnt vmcnt(9) so 9-18 loads stay in flight ACROSS the waits (T4).
// LDS dest is linear (lane*16, rule #21); the bank-deconflict swizzle is in
// the per-lane GLOBAL source address (scol = f4 ^ ((row>>1)&3)), matched on
// the ds_read side -> 2-way max aliasing (free).
//
// ws layout (floats): q | wtil | scores | concat | integ | fcwt
// LESSONS (R4..R14): pad multiple of 16B; depth-2 prefetch, k=4/k=16,
// 32-col chunks, zero-LDS all regressed; reg-staged path pinned at ~290 us
// by the wave-issued staging + vmcnt(0) drain structure.
// ---------------------------------------------------------------------------

__device__ __forceinline__ float waveMax(float v) {
    #pragma unroll
    for (int off = 32; off > 0; off >>= 1) v = fmaxf(v, __shfl_xor(v, off, 64));
    return v;
}
__device__ __forceinline__ float waveSum(float v) {
    #pragma unroll
    for (int off = 32; off > 0; off >>= 1) v += __shfl_xor(v, off, 64);
    return v;
}

typedef const __attribute__((address_space(1))) void gas_void;
typedef __attribute__((address_space(3))) void las_void;

// 16 B/lane direct global->LDS copy. LDS dest = uniform base + lane*16.
__device__ __forceinline__ void async_ld16(const float* g, float* l) {
    __builtin_amdgcn_global_load_lds((gas_void*)(uintptr_t)g,
                                     (las_void*)(uint32_t)(uintptr_t)l,
                                     16, 0, 0);
}

// ---- Kernel A: q[b, col] = sum_m x[b, idx, m] * Wq[m, col] -----------------
// grid (4 col-chunks, 64 b), block 256
__global__ void k_q(const float* __restrict__ x, const float* __restrict__ wq,
                    const int* __restrict__ idxp, float* __restrict__ qout, int sfull) {
    const int tid = threadIdx.x;
    const int col = blockIdx.x * 256 + tid;
    const int b   = blockIdx.y;
    const int idx = *idxp;
    const float* xr = x + ((size_t)b * sfull + idx) * MD;   // uniform -> scalar loads
    float a0 = 0.f, a1 = 0.f, a2 = 0.f, a3 = 0.f;
    for (int m = 0; m < MD; m += 4) {
        a0 += xr[m]     * wq[(size_t)m * MD + col];
        a1 += xr[m + 1] * wq[(size_t)(m + 1) * MD + col];
        a2 += xr[m + 2] * wq[(size_t)(m + 2) * MD + col];
        a3 += xr[m + 3] * wq[(size_t)(m + 3) * MD + col];
    }
    qout[(size_t)b * MD + col] = (a0 + a1) + (a2 + a3);
}

// ---- Kernel B: wtil[b,h,m] = sum_d Wk[m, h*64+d] * q[b, h*64+d] ------------
// grid (16 h, 32 b-groups of 2), block 256
__global__ void k_wtil(const float* __restrict__ wk, const float* __restrict__ q,
                       float* __restrict__ wtil) {
    const int tid = threadIdx.x;
    const int h  = blockIdx.x;
    const int b0 = blockIdx.y * 2;
    for (int mi = 0; mi < 4; ++mi) {
        const int m = mi * 256 + tid;
        const float4* wrow = (const float4*)(wk + (size_t)m * MD + h * D_);
        float4 wv[16];
        #pragma unroll
        for (int j = 0; j < 16; ++j) wv[j] = wrow[j];
        #pragma unroll
        for (int bb = 0; bb < 2; ++bb) {
            const float* qh = q + (size_t)(b0 + bb) * MD + h * D_;  // uniform -> s_load
            float acc = 0.f;
            #pragma unroll
            for (int j = 0; j < 16; ++j)
                acc += wv[j].x * qh[4*j] + wv[j].y * qh[4*j+1]
                     + wv[j].z * qh[4*j+2] + wv[j].w * qh[4*j+3];
            wtil[((size_t)(b0 + bb) * H_ + h) * MD + m] = acc;
        }
    }
}

// ---- Kernel P1: scores[b,h,s] = (x[b,s,:] . wtil[b,h,:]) / 8 ---------------
// grid (64 b, sfull/512 s-tiles), block 256 (4 waves), wave owns 128 rows.
// Per 16-col chunk: 9 global_load_lds (8 X-ops + 1 W-op, 16 B/lane) into a
// wave-private double buffer; counted vmcnt(9) overlaps the older buffer's
// compute with the newer buffer's loads. 48 ds_read_b128 + 256 FMA consume.
// Source-side XOR swizzle (scol = f4 ^ ((row>>1)&3)) -> 2-way reads (free).
// Zero barriers; phase-ring stagger; XCD-b grid placement (b = blockIdx.x).
__global__ __launch_bounds__(256) void k_scores(
        const float* __restrict__ x, const float* __restrict__ wtil,
        const int* __restrict__ idxp, float* __restrict__ scores, int sfull) {
    __shared__ __align__(16) float LDS[4][2][2304];  // per-wave 2 x 9 KB
    const int tid  = threadIdx.x;
    const int w    = tid >> 6;
    const int lane = tid & 63;
    const int sg   = lane & 15;      // s sub-index
    const int hg   = lane >> 4;      // h group
    const int b    = blockIdx.x;
    const int sblk = blockIdx.y * 512;
    const int s0   = sblk + w * 128; // this wave's first row
    const int S    = *idxp + 1;
    if (sblk >= S) return;

    const float* xb = x    + (size_t)b * sfull * MD;
    const float* wb = wtil + (size_t)b * H_ * MD;

    float* bufA = LDS[w][0];
    float* bufB = LDS[w][1];

    // per-lane global offsets for the 9 DMA ops (chunk-invariant part).
    // op i covers physical granules [i*64, (i+1)*64): lane l -> granule
    // p = i*64+l -> row = p>>2, scol = p&3, logical f4 = scol ^ ((row>>1)&3).
    int xgoff[8];
    #pragma unroll
    for (int i = 0; i < 8; ++i) {
        const int p    = i * 64 + lane;
        const int row  = p >> 2;
        const int scol = p & 3;
        const int f4   = scol ^ ((row >> 1) & 3);
        int srw = s0 + row; if (srw >= S) srw = S - 1;   // clamp (store guarded)
        xgoff[i] = srw * MD + f4 * 4;
    }
    const float* wbp = wb + (size_t)(lane >> 2) * MD + (lane & 3) * 4;  // W linear

    const int xkey = (sg >> 1) & 3;  // read-side swizzle key (lane-constant)

    // per-wave chunk-ring phase: decorrelate HBM channel usage
    const int phase = (b + blockIdx.y * 8 + w) & 63;
#define MCOF(T) ((((T) + phase) & 63) * 16)

    float acc[8][4] = {};

#define ISSUE(BUF, MC) do {                                                    \
        _Pragma("unroll")                                                      \
        for (int i = 0; i < 8; ++i)                                            \
            async_ld16(xb + xgoff[i] + (MC), (BUF) + i * 256);                 \
        async_ld16(wbp + (MC), (BUF) + 2048);                                  \
    } while (0)

#define COMPUTE(BUF) do {                                                      \
        const float* Xs = (BUF);                                               \
        const float* Ws = (BUF) + 2048;                                        \
        _Pragma("unroll")                                                      \
        for (int half = 0; half < 2; ++half) {                                 \
            float4 wrh[4][2];                                                  \
            _Pragma("unroll")                                                  \
            for (int j = 0; j < 4; ++j) {                                      \
                _Pragma("unroll")                                              \
                for (int mm = 0; mm < 2; ++mm)                                 \
                    wrh[j][mm] = *(const float4*)(&Ws[(hg + 4 * j) * 16 + (half * 2 + mm) * 4]); \
            }                                                                  \
            _Pragma("unroll")                                                  \
            for (int k = 0; k < 8; ++k) {                                      \
                const int xrow = sg + 16 * k;                                  \
                const float4 xr0 = *(const float4*)(&Xs[xrow * 16 + ((half * 2)     ^ xkey) * 4]); \
                const float4 xr1 = *(const float4*)(&Xs[xrow * 16 + ((half * 2 + 1) ^ xkey) * 4]); \
                _Pragma("unroll")                                              \
                for (int j = 0; j < 4; ++j) {                                  \
                    acc[k][j] += xr0.x * wrh[j][0].x + xr0.y * wrh[j][0].y     \
                               + xr0.z * wrh[j][0].z + xr0.w * wrh[j][0].w     \
                               + xr1.x * wrh[j][1].x + xr1.y * wrh[j][1].y     \
                               + xr1.z * wrh[j][1].z + xr1.w * wrh[j][1].w;    \
                }                                                              \
            }                                                                  \
        }                                                                      \
    } while (0)

    ISSUE(bufA, MCOF(0));

    for (int t = 0; t < 64; t += 2) {
        ISSUE(bufB, MCOF(t + 1));                       // 18 loads in flight
        asm volatile("s_waitcnt vmcnt(9)" ::: "memory"); // oldest 9 (bufA) done
        COMPUTE(bufA);                                   // chunk t
        asm volatile("s_waitcnt lgkmcnt(0)" ::: "memory"); // ds_reads done (WAR)
        if (t + 2 < 64) {
            ISSUE(bufA, MCOF(t + 2));
            asm volatile("s_waitcnt vmcnt(9)" ::: "memory"); // bufB done
        } else {
            asm volatile("s_waitcnt vmcnt(0)" ::: "memory");
        }
        COMPUTE(bufB);                                   // chunk t+1
        asm volatile("s_waitcnt lgkmcnt(0)" ::: "memory"); // WAR vs next ISSUE
    }
#undef ISSUE
#undef COMPUTE
#undef MCOF

    #pragma unroll
    for (int k = 0; k < 8; ++k) {
        const int s = s0 + sg + 16 * k;
        if (s < S) {
            #pragma unroll
            for (int j = 0; j < 4; ++j)
                scores[((size_t)b * H_ + (hg + 4 * j)) * sfull + s] = acc[k][j] * 0.125f;
        }
    }
}

// ---- Kernel C: softmax over s + sparse gather y = attn^T x + Wv projection -
// grid (16 h, 64 b), block 256
__global__ void k_attn(const float* __restrict__ x, const float* __restrict__ scores,
                       const float* __restrict__ wv, const int* __restrict__ idxp,
                       float* __restrict__ concat, int sfull) {
    __shared__ float red[8];
    __shared__ int   scanw[4];
    __shared__ int   lidx[4096];
    __shared__ float lw[4096];
    __shared__ float ylds[1024];
    __shared__ float pred[256];

    const int tid = threadIdx.x;
    const int h = blockIdx.x, b = blockIdx.y;
    const int S = *idxp + 1;
    const float* sc = scores + ((size_t)b * H_ + h) * sfull;

    float ls[16];
    float mx = -INFINITY;
    #pragma unroll
    for (int k = 0; k < 16; ++k) {
        int s = tid + 256 * k;
        if (s < S) { ls[k] = sc[s]; mx = fmaxf(mx, ls[k]); }
        else ls[k] = -INFINITY;
    }
    // block max
    mx = waveMax(mx);
    const int wid = tid >> 6, lane = tid & 63;
    if (lane == 0) red[wid] = mx;
    __syncthreads();
    mx = fmaxf(fmaxf(red[0], red[1]), fmaxf(red[2], red[3]));

    // denom + significant count (exp(s-max) <= 1.7e-15 contributes nothing)
    float sum = 0.f; int cnt = 0;
    #pragma unroll
    for (int k = 0; k < 16; ++k) {
        if (ls[k] > -INFINITY) {
            float e = ls[k] - mx;
            sum += expf(e);
            if (e > -34.f) ++cnt;
        }
    }
    sum = waveSum(sum);
    __syncthreads();
    if (lane == 0) red[4 + wid] = sum;
    __syncthreads();
    const float inv = 1.f / (red[4] + red[5] + red[6] + red[7]);

    // deterministic compaction: wave-level shfl scan + cross-wave LDS (1 barrier)
    int inc = cnt;
    #pragma unroll
    for (int off = 1; off < 64; off <<= 1) {
        int t = __shfl_up(inc, off, 64);
        if (lane >= off) inc += t;
    }
    if (lane == 63) scanw[wid] = inc;
    __syncthreads();
    int wbase = 0, total = 0;
    #pragma unroll
    for (int ww = 0; ww < 4; ++ww) {
        int t = scanw[ww];
        if (ww < wid) wbase += t;
        total += t;
    }
    int pos = wbase + inc - cnt;
    #pragma unroll
    for (int k = 0; k < 16; ++k) {
        if (ls[k] > -INFINITY) {
            float e = ls[k] - mx;
            if (e > -34.f) { lidx[pos] = tid + 256 * k; lw[pos] = expf(e) * inv; ++pos; }
        }
    }
    __syncthreads();

    // y[m] = sum_{significant s} attn * x[b,s,m]  (typically 1-3 rows)
    float4 acc = make_float4(0.f, 0.f, 0.f, 0.f);
    const float* xb = x + (size_t)b * sfull * MD;
    for (int e = 0; e < total; ++e) {
        int s = lidx[e]; float w = lw[e];
        float4 xv = *(const float4*)(xb + (size_t)s * MD + tid * 4);
        acc.x += w * xv.x; acc.y += w * xv.y; acc.z += w * xv.z; acc.w += w * xv.w;
    }
    *(float4*)(&ylds[tid * 4]) = acc;
    __syncthreads();

    // head_out[d] = sum_m y[m] * Wv[m, h*64+d]
    const int d = tid & 63, g = tid >> 6;
    const float* wcol = wv + (size_t)h * D_ + d;
    float part = 0.f;
    for (int m = g * 256; m < g * 256 + 256; ++m)
        part += ylds[m] * wcol[(size_t)m * MD];
    pred[tid] = part;
    __syncthreads();
    if (tid < 64) {
        float v = pred[tid] + pred[tid + 64] + pred[tid + 128] + pred[tid + 192];
        concat[(size_t)b * MD + h * D_ + tid] = v;
    }
}

// ---- Kernel T: fcwt[m][n] = fcW[n][m] --------------------------------------
__global__ void k_transpose(const float* __restrict__ a, float* __restrict__ at) {
    __shared__ float t[32][33];
    const int bx = blockIdx.x * 32, by = blockIdx.y * 32;
    const int tx = threadIdx.x & 31, ty = threadIdx.x >> 5;  // 32x8
    for (int r = ty; r < 32; r += 8)
        t[r][tx] = a[(size_t)(by + r) * MD + bx + tx];
    __syncthreads();
    for (int r = ty; r < 32; r += 8)
        at[(size_t)(bx + r) * MD + by + tx] = t[tx][r];
}

// ---- Kernel D: integ[b,n] = sum_m concat[b,m] * fcW[n,m] + bias[n] ---------
// grid (64 b, 16 n-chunks of 64), block 256: 4-way m-split + LDS reduce.
__global__ void k_fc(const float* __restrict__ concat, const float* __restrict__ fcwt,
                     const float* __restrict__ bias, float* __restrict__ integ) {
    __shared__ float c[1024];
    __shared__ float pred[256];
    const int tid = threadIdx.x, b = blockIdx.x;
    const int n0 = blockIdx.y * 64;
    const int nl = tid & 63, mg = tid >> 6;
    #pragma unroll
    for (int k = 0; k < 4; ++k) c[tid + 256 * k] = concat[(size_t)b * MD + tid + 256 * k];
    __syncthreads();
    const int mbase = mg * 256;
    float a0 = 0.f, a1 = 0.f, a2 = 0.f, a3 = 0.f;
    for (int m = 0; m < 256; m += 4) {
        a0 += c[mbase + m]     * fcwt[(size_t)(mbase + m) * MD + n0 + nl];
        a1 += c[mbase + m + 1] * fcwt[(size_t)(mbase + m + 1) * MD + n0 + nl];
        a2 += c[mbase + m + 2] * fcwt[(size_t)(mbase + m + 2) * MD + n0 + nl];
        a3 += c[mbase + m + 3] * fcwt[(size_t)(mbase + m + 3) * MD + n0 + nl];
    }
    pred[tid] = (a0 + a1) + (a2 + a3);
    __syncthreads();
    if (tid < 64)
        integ[(size_t)b * MD + n0 + tid] =
            pred[tid] + pred[tid + 64] + pred[tid + 128] + pred[tid + 192] + bias[n0 + tid];
}

// ---- Kernel E: LayerNorm ---------------------------------------------------
__global__ void k_ln(const float* __restrict__ integ, const float* __restrict__ gamma,
                     const float* __restrict__ beta, float* __restrict__ out) {
    __shared__ float red[8];
    const int tid = threadIdx.x, b = blockIdx.x;
    float v[4];
    #pragma unroll
    for (int k = 0; k < 4; ++k) v[k] = integ[(size_t)b * MD + tid + 256 * k];
    float s = v[0] + v[1] + v[2] + v[3];
    s = waveSum(s);
    const int wid = tid >> 6, lane = tid & 63;
    if (lane == 0) red[wid] = s;
    __syncthreads();
    const float mean = (red[0] + red[1] + red[2] + red[3]) * (1.f / MD);
    float q = 0.f;
    #pragma unroll
    for (int k = 0; k < 4; ++k) { float d = v[k] - mean; q += d * d; }
    q = waveSum(q);
    __syncthreads();
    if (lane == 0) red[4 + wid] = q;
    __syncthreads();
    const float var = (red[4] + red[5] + red[6] + red[7]) * (1.f / MD);
    const float rs = rsqrtf(var + LNEPS);
    #pragma unroll
    for (int k = 0; k < 4; ++k) {
        int i = tid + 256 * k;
        out[(size_t)b * MD + i] = (v[k] - mean) * rs * gamma[i] + beta[i];
    }
}

extern "C" void kernel_launch(void* const* d_in, const int* in_sizes, int n_in,
                              void* d_out, int out_size, void* d_ws, size_t ws_size,
                              hipStream_t stream) {
    const float* x     = (const float*)d_in[0];
    const float* wq    = (const float*)d_in[1];
    const float* wk    = (const float*)d_in[2];
    const float* wvp   = (const float*)d_in[3];
    const float* fcw   = (const float*)d_in[4];
    const float* fcb   = (const float*)d_in[5];
    const float* gamma = (const float*)d_in[6];
    const float* beta  = (const float*)d_in[7];
    const int*   idxp  = (const int*)d_in[8];
    float* out = (float*)d_out;

    const int sfull = in_sizes[0] / (B_ * MD);   // 4096

    float* q      = (float*)d_ws;
    float* wtil   = q      + (size_t)B_ * MD;
    float* scores = wtil   + (size_t)B_ * H_ * MD;
    float* concat = scores + (size_t)B_ * H_ * sfull;
    float* integ  = concat + (size_t)B_ * MD;
    float* fcwt   = integ  + (size_t)B_ * MD;

    hipLaunchKernelGGL(k_q,         dim3(4, 64),           dim3(256), 0, stream, x, wq, idxp, q, sfull);
    hipLaunchKernelGGL(k_wtil,      dim3(16, 32),          dim3(256), 0, stream, wk, q, wtil);
    hipLaunchKernelGGL(k_scores,    dim3(B_, (sfull + 511) / 512), dim3(256), 0, stream, x, wtil, idxp, scores, sfull);
    hipLaunchKernelGGL(k_transpose, dim3(32, 32),          dim3(256), 0, stream, fcw, fcwt);
    hipLaunchKernelGGL(k_attn,      dim3(H_, B_),          dim3(256), 0, stream, x, scores, wvp, idxp, concat, sfull);
    hipLaunchKernelGGL(k_fc,        dim3(64, 16),          dim3(256), 0, stream, concat, fcwt, fcb, integ);
    hipLaunchKernelGGL(k_ln,        dim3(B_),              dim3(256), 0, stream, integ, gamma, beta, out);
}

// Round 17
// 349.432 us; speedup vs baseline: 1.0730x; 1.0730x over previous
//
#include <hip/hip_runtime.h>
#include <math.h>

#define B_   64
#define MD   1024
#define H_   16
#define D_   64
#define LNEPS 1e-5f

// ---------------------------------------------------------------------------
// FINAL CHAMPION (R11 structure; reproduced 346/349 us over two runs).
// k_scores = v5 body (k=8, wave-private LDS, pad 20, zero barriers, depth-1
// prefetch) + phase-ring stagger + XCD-b grid transpose.
//
// ws layout (floats): q | wtil | scores | concat | integ | fcwt
//
// SESSION LEDGER (k_scores ~290 us vs 170 us HBM floor; every lever tried):
//  - barriers removed (R4): neutral        - LDS-op halving (R5): -17
//  - full-line 32-col chunks (R7): +59     - XCD swizzle (R8): -10
//  - pad 17 misalign (R9): +480 (LESSON: pad must be multiple of 16 B)
//  - depth-2 prefetch (R10): +23           - channel stagger (R11): -8
//  - zero-LDS scalar-W (R12): +1350 (divergent addrs -> spill)
//  - k=4 / 16 waves-CU (R13): +23          - k=16 / min LDS-ops (R14): +17
//  - global_load_lds + counted vmcnt (R16): +26
//  - bf16/MFMA scores numerically unsafe (softmax winner flips).
// Binder: fp32 s<->m transpose forces LDS staging; wave-issued stage +
// waitcnt drain serializes ~35% of LDS time onto the HBM stream. Practical
// plateau ~2x the x-stream floor for this structure in HIP source.
// ---------------------------------------------------------------------------

__device__ __forceinline__ float waveMax(float v) {
    #pragma unroll
    for (int off = 32; off > 0; off >>= 1) v = fmaxf(v, __shfl_xor(v, off, 64));
    return v;
}
__device__ __forceinline__ float waveSum(float v) {
    #pragma unroll
    for (int off = 32; off > 0; off >>= 1) v += __shfl_xor(v, off, 64);
    return v;
}

// ---- Kernel A: q[b, col] = sum_m x[b, idx, m] * Wq[m, col] -----------------
// grid (4 col-chunks, 64 b), block 256
__global__ void k_q(const float* __restrict__ x, const float* __restrict__ wq,
                    const int* __restrict__ idxp, float* __restrict__ qout, int sfull) {
    const int tid = threadIdx.x;
    const int col = blockIdx.x * 256 + tid;
    const int b   = blockIdx.y;
    const int idx = *idxp;
    const float* xr = x + ((size_t)b * sfull + idx) * MD;   // uniform -> scalar loads
    float a0 = 0.f, a1 = 0.f, a2 = 0.f, a3 = 0.f;
    for (int m = 0; m < MD; m += 4) {
        a0 += xr[m]     * wq[(size_t)m * MD + col];
        a1 += xr[m + 1] * wq[(size_t)(m + 1) * MD + col];
        a2 += xr[m + 2] * wq[(size_t)(m + 2) * MD + col];
        a3 += xr[m + 3] * wq[(size_t)(m + 3) * MD + col];
    }
    qout[(size_t)b * MD + col] = (a0 + a1) + (a2 + a3);
}

// ---- Kernel B: wtil[b,h,m] = sum_d Wk[m, h*64+d] * q[b, h*64+d] ------------
// grid (16 h, 32 b-groups of 2), block 256
__global__ void k_wtil(const float* __restrict__ wk, const float* __restrict__ q,
                       float* __restrict__ wtil) {
    const int tid = threadIdx.x;
    const int h  = blockIdx.x;
    const int b0 = blockIdx.y * 2;
    for (int mi = 0; mi < 4; ++mi) {
        const int m = mi * 256 + tid;
        const float4* wrow = (const float4*)(wk + (size_t)m * MD + h * D_);
        float4 wv[16];
        #pragma unroll
        for (int j = 0; j < 16; ++j) wv[j] = wrow[j];
        #pragma unroll
        for (int bb = 0; bb < 2; ++bb) {
            const float* qh = q + (size_t)(b0 + bb) * MD + h * D_;  // uniform -> s_load
            float acc = 0.f;
            #pragma unroll
            for (int j = 0; j < 16; ++j)
                acc += wv[j].x * qh[4*j] + wv[j].y * qh[4*j+1]
                     + wv[j].z * qh[4*j+2] + wv[j].w * qh[4*j+3];
            wtil[((size_t)(b0 + bb) * H_ + h) * MD + m] = acc;
        }
    }
}

// ---- Kernel P1: scores[b,h,s] = (x[b,s,:] . wtil[b,h,:]) / 8 ---------------
// grid (64 b, sfull/512 s-tiles), block 256.
// Wave-private LDS, zero barriers, k=8 rows/thread, 16-col chunks, depth-1
// register prefetch, per-wave chunk-ring phase stagger (HBM channel
// decorrelation), grid transposed so linear id = b + 64*sy -> XCD = b%8
// (wtil slice stays L2-resident while x streams).
__global__ __launch_bounds__(256) void k_scores(
        const float* __restrict__ x, const float* __restrict__ wtil,
        const int* __restrict__ idxp, float* __restrict__ scores, int sfull) {
    __shared__ float Xw[4][128 * 20];  // per-wave: 128 rows x 16 m (+4 pad) = 10 KB
    __shared__ float Ww[4][16 * 20];   // per-wave: 16 h x 16 m (+4 pad) = 1.25 KB
    const int tid  = threadIdx.x;
    const int w    = tid >> 6;
    const int lane = tid & 63;
    const int sg   = lane & 15;      // s sub-index
    const int hg   = lane >> 4;      // h group
    const int b    = blockIdx.x;
    const int sblk = blockIdx.y * 512;
    const int s0   = sblk + w * 128; // this wave's first row
    const int S    = *idxp + 1;
    if (sblk >= S) return;

    const float* xb = x    + (size_t)b * sfull * MD;
    const float* wb = wtil + (size_t)b * H_ * MD;

    float* Xs = Xw[w];
    float* Ws = Ww[w];

    const int csl = lane >> 2;       // 0..15 staging row within group
    const int cf4 = lane & 3;        // 0..3 float4 slot

    // per-wave chunk-ring phase: decorrelate HBM channel usage
    const int phase = (b + blockIdx.y * 8 + w) & 63;
#define MCOF(T) ((((T) + phase) & 63) * 16)

    float acc[8][4] = {};
    float4 nx[8];
    float4 nw;

#define ISSUE(MC) do {                                                         \
        _Pragma("unroll")                                                      \
        for (int i = 0; i < 8; ++i) {                                          \
            int sl = i * 16 + csl;                                             \
            int srow = s0 + sl;                                                \
            nx[i] = (srow < S)                                                 \
                ? *(const float4*)(xb + (size_t)srow * MD + (MC) + cf4 * 4)    \
                : make_float4(0.f, 0.f, 0.f, 0.f);                             \
        }                                                                      \
        nw = *(const float4*)(wb + (size_t)csl * MD + (MC) + cf4 * 4);         \
    } while (0)

    ISSUE(MCOF(0));

    for (int t = 0; t < 64; ++t) {
        // commit staged regs to this wave's LDS slice (in-order after last
        // chunk's ds_reads; wave-private so no cross-wave hazard)
        #pragma unroll
        for (int i = 0; i < 8; ++i)
            *(float4*)(&Xs[(i * 16 + csl) * 20 + cf4 * 4]) = nx[i];
        *(float4*)(&Ws[csl * 20 + cf4 * 4]) = nw;

        if (t + 1 < 64) ISSUE(MCOF(t + 1));   // prefetch next ring chunk

        // compute 8s x 4h x 16m, in two 8-m halves to cap register pressure
        #pragma unroll
        for (int half = 0; half < 2; ++half) {
            float4 wrh[4][2];
            #pragma unroll
            for (int j = 0; j < 4; ++j) {
                #pragma unroll
                for (int mm = 0; mm < 2; ++mm)
                    wrh[j][mm] = *(const float4*)(&Ws[(hg + 4 * j) * 20 + (half * 2 + mm) * 4]);
            }
            #pragma unroll
            for (int k = 0; k < 8; ++k) {
                const float4 xr0 = *(const float4*)(&Xs[(sg + 16 * k) * 20 + (half * 2) * 4]);
                const float4 xr1 = *(const float4*)(&Xs[(sg + 16 * k) * 20 + (half * 2 + 1) * 4]);
                #pragma unroll
                for (int j = 0; j < 4; ++j) {
                    acc[k][j] += xr0.x * wrh[j][0].x + xr0.y * wrh[j][0].y
                               + xr0.z * wrh[j][0].z + xr0.w * wrh[j][0].w
                               + xr1.x * wrh[j][1].x + xr1.y * wrh[j][1].y
                               + xr1.z * wrh[j][1].z + xr1.w * wrh[j][1].w;
                }
            }
        }
    }
#undef ISSUE
#undef MCOF

    #pragma unroll
    for (int k = 0; k < 8; ++k) {
        const int s = s0 + sg + 16 * k;
        if (s < S) {
            #pragma unroll
            for (int j = 0; j < 4; ++j)
                scores[((size_t)b * H_ + (hg + 4 * j)) * sfull + s] = acc[k][j] * 0.125f;
        }
    }
}

// ---- Kernel C: softmax over s + sparse gather y = attn^T x + Wv projection -
// grid (16 h, 64 b), block 256
__global__ void k_attn(const float* __restrict__ x, const float* __restrict__ scores,
                       const float* __restrict__ wv, const int* __restrict__ idxp,
                       float* __restrict__ concat, int sfull) {
    __shared__ float red[8];
    __shared__ int   scanw[4];
    __shared__ int   lidx[4096];
    __shared__ float lw[4096];
    __shared__ float ylds[1024];
    __shared__ float pred[256];

    const int tid = threadIdx.x;
    const int h = blockIdx.x, b = blockIdx.y;
    const int S = *idxp + 1;
    const float* sc = scores + ((size_t)b * H_ + h) * sfull;

    float ls[16];
    float mx = -INFINITY;
    #pragma unroll
    for (int k = 0; k < 16; ++k) {
        int s = tid + 256 * k;
        if (s < S) { ls[k] = sc[s]; mx = fmaxf(mx, ls[k]); }
        else ls[k] = -INFINITY;
    }
    // block max
    mx = waveMax(mx);
    const int wid = tid >> 6, lane = tid & 63;
    if (lane == 0) red[wid] = mx;
    __syncthreads();
    mx = fmaxf(fmaxf(red[0], red[1]), fmaxf(red[2], red[3]));

    // denom + significant count (exp(s-max) <= 1.7e-15 contributes nothing)
    float sum = 0.f; int cnt = 0;
    #pragma unroll
    for (int k = 0; k < 16; ++k) {
        if (ls[k] > -INFINITY) {
            float e = ls[k] - mx;
            sum += expf(e);
            if (e > -34.f) ++cnt;
        }
    }
    sum = waveSum(sum);
    __syncthreads();
    if (lane == 0) red[4 + wid] = sum;
    __syncthreads();
    const float inv = 1.f / (red[4] + red[5] + red[6] + red[7]);

    // deterministic compaction: wave-level shfl scan + cross-wave LDS (1 barrier)
    int inc = cnt;
    #pragma unroll
    for (int off = 1; off < 64; off <<= 1) {
        int t = __shfl_up(inc, off, 64);
        if (lane >= off) inc += t;
    }
    if (lane == 63) scanw[wid] = inc;
    __syncthreads();
    int wbase = 0, total = 0;
    #pragma unroll
    for (int ww = 0; ww < 4; ++ww) {
        int t = scanw[ww];
        if (ww < wid) wbase += t;
        total += t;
    }
    int pos = wbase + inc - cnt;
    #pragma unroll
    for (int k = 0; k < 16; ++k) {
        if (ls[k] > -INFINITY) {
            float e = ls[k] - mx;
            if (e > -34.f) { lidx[pos] = tid + 256 * k; lw[pos] = expf(e) * inv; ++pos; }
        }
    }
    __syncthreads();

    // y[m] = sum_{significant s} attn * x[b,s,m]  (typically 1-3 rows)
    float4 acc = make_float4(0.f, 0.f, 0.f, 0.f);
    const float* xb = x + (size_t)b * sfull * MD;
    for (int e = 0; e < total; ++e) {
        int s = lidx[e]; float w = lw[e];
        float4 xv = *(const float4*)(xb + (size_t)s * MD + tid * 4);
        acc.x += w * xv.x; acc.y += w * xv.y; acc.z += w * xv.z; acc.w += w * xv.w;
    }
    *(float4*)(&ylds[tid * 4]) = acc;
    __syncthreads();

    // head_out[d] = sum_m y[m] * Wv[m, h*64+d]
    const int d = tid & 63, g = tid >> 6;
    const float* wcol = wv + (size_t)h * D_ + d;
    float part = 0.f;
    for (int m = g * 256; m < g * 256 + 256; ++m)
        part += ylds[m] * wcol[(size_t)m * MD];
    pred[tid] = part;
    __syncthreads();
    if (tid < 64) {
        float v = pred[tid] + pred[tid + 64] + pred[tid + 128] + pred[tid + 192];
        concat[(size_t)b * MD + h * D_ + tid] = v;
    }
}

// ---- Kernel T: fcwt[m][n] = fcW[n][m] --------------------------------------
__global__ void k_transpose(const float* __restrict__ a, float* __restrict__ at) {
    __shared__ float t[32][33];
    const int bx = blockIdx.x * 32, by = blockIdx.y * 32;
    const int tx = threadIdx.x & 31, ty = threadIdx.x >> 5;  // 32x8
    for (int r = ty; r < 32; r += 8)
        t[r][tx] = a[(size_t)(by + r) * MD + bx + tx];
    __syncthreads();
    for (int r = ty; r < 32; r += 8)
        at[(size_t)(bx + r) * MD + by + tx] = t[tx][r];
}

// ---- Kernel D: integ[b,n] = sum_m concat[b,m] * fcW[n,m] + bias[n] ---------
// grid (64 b, 16 n-chunks of 64), block 256: 4-way m-split + LDS reduce.
__global__ void k_fc(const float* __restrict__ concat, const float* __restrict__ fcwt,
                     const float* __restrict__ bias, float* __restrict__ integ) {
    __shared__ float c[1024];
    __shared__ float pred[256];
    const int tid = threadIdx.x, b = blockIdx.x;
    const int n0 = blockIdx.y * 64;
    const int nl = tid & 63, mg = tid >> 6;
    #pragma unroll
    for (int k = 0; k < 4; ++k) c[tid + 256 * k] = concat[(size_t)b * MD + tid + 256 * k];
    __syncthreads();
    const int mbase = mg * 256;
    float a0 = 0.f, a1 = 0.f, a2 = 0.f, a3 = 0.f;
    for (int m = 0; m < 256; m += 4) {
        a0 += c[mbase + m]     * fcwt[(size_t)(mbase + m) * MD + n0 + nl];
        a1 += c[mbase + m + 1] * fcwt[(size_t)(mbase + m + 1) * MD + n0 + nl];
        a2 += c[mbase + m + 2] * fcwt[(size_t)(mbase + m + 2) * MD + n0 + nl];
        a3 += c[mbase + m + 3] * fcwt[(size_t)(mbase + m + 3) * MD + n0 + nl];
    }
    pred[tid] = (a0 + a1) + (a2 + a3);
    __syncthreads();
    if (tid < 64)
        integ[(size_t)b * MD + n0 + tid] =
            pred[tid] + pred[tid + 64] + pred[tid + 128] + pred[tid + 192] + bias[n0 + tid];
}

// ---- Kernel E: LayerNorm ---------------------------------------------------
__global__ void k_ln(const float* __restrict__ integ, const float* __restrict__ gamma,
                     const float* __restrict__ beta, float* __restrict__ out) {
    __shared__ float red[8];
    const int tid = threadIdx.x, b = blockIdx.x;
    float v[4];
    #pragma unroll
    for (int k = 0; k < 4; ++k) v[k] = integ[(size_t)b * MD + tid + 256 * k];
    float s = v[0] + v[1] + v[2] + v[3];
    s = waveSum(s);
    const int wid = tid >> 6, lane = tid & 63;
    if (lane == 0) red[wid] = s;
    __syncthreads();
    const float mean = (red[0] + red[1] + red[2] + red[3]) * (1.f / MD);
    float q = 0.f;
    #pragma unroll
    for (int k = 0; k < 4; ++k) { float d = v[k] - mean; q += d * d; }
    q = waveSum(q);
    __syncthreads();
    if (lane == 0) red[4 + wid] = q;
    __syncthreads();
    const float var = (red[4] + red[5] + red[6] + red[7]) * (1.f / MD);
    const float rs = rsqrtf(var + LNEPS);
    #pragma unroll
    for (int k = 0; k < 4; ++k) {
        int i = tid + 256 * k;
        out[(size_t)b * MD + i] = (v[k] - mean) * rs * gamma[i] + beta[i];
    }
}

extern "C" void kernel_launch(void* const* d_in, const int* in_sizes, int n_in,
                              void* d_out, int out_size, void* d_ws, size_t ws_size,
                              hipStream_t stream) {
    const float* x     = (const float*)d_in[0];
    const float* wq    = (const float*)d_in[1];
    const float* wk    = (const float*)d_in[2];
    const float* wvp   = (const float*)d_in[3];
    const float* fcw   = (const float*)d_in[4];
    const float* fcb   = (const float*)d_in[5];
    const float* gamma = (const float*)d_in[6];
    const float* beta  = (const float*)d_in[7];
    const int*   idxp  = (const int*)d_in[8];
    float* out = (float*)d_out;

    const int sfull = in_sizes[0] / (B_ * MD);   // 4096

    float* q      = (float*)d_ws;
    float* wtil   = q      + (size_t)B_ * MD;
    float* scores = wtil   + (size_t)B_ * H_ * MD;
    float* concat = scores + (size_t)B_ * H_ * sfull;
    float* integ  = concat + (size_t)B_ * MD;
    float* fcwt   = integ  + (size_t)B_ * MD;

    hipLaunchKernelGGL(k_q,         dim3(4, 64),           dim3(256), 0, stream, x, wq, idxp, q, sfull);
    hipLaunchKernelGGL(k_wtil,      dim3(16, 32),          dim3(256), 0, stream, wk, q, wtil);
    hipLaunchKernelGGL(k_scores,    dim3(B_, (sfull + 511) / 512), dim3(256), 0, stream, x, wtil, idxp, scores, sfull);
    hipLaunchKernelGGL(k_transpose, dim3(32, 32),          dim3(256), 0, stream, fcw, fcwt);
    hipLaunchKernelGGL(k_attn,      dim3(H_, B_),          dim3(256), 0, stream, x, scores, wvp, idxp, concat, sfull);
    hipLaunchKernelGGL(k_fc,        dim3(64, 16),          dim3(256), 0, stream, concat, fcwt, fcb, integ);
    hipLaunchKernelGGL(k_ln,        dim3(B_),              dim3(256), 0, stream, integ, gamma, beta, out);
}

// Round 18
// 305.085 us; speedup vs baseline: 1.2289x; 1.1454x over previous
//
#include <hip/hip_runtime.h>
#include <math.h>

#define B_   64
#define MD   1024
#define H_   16
#define D_   64
#define LNEPS 1e-5f

// ---------------------------------------------------------------------------
// v17: champion tail + k_scores rebuilt on split-bf16 MFMA.
// scores = (xh+xl)·(wh+wl) via 3 passes mfma_f32_16x16x32_bf16 (drop xl·wl).
// Error budget: bf16 products exact in fp32 acc; representation 2^-17 rel;
// dropped term ~0.003 on scores std ~1024, top-2 gaps ~300 -> winner safe.
// Per 32-col window/wave: 18 b128 LDS writes + 18 b128 frag reads (vs 114
// fp32 ops) -- 3.2x less LDS traffic; 512 FMA -> 24 MFMA (matrix pipe).
// D-orientation: A=w-tilde, B=x^T -> D[h][s]: h=(lane>>4)*4+reg, s=lane&15
// (m89-verified C/D mapping) -> coalesced stores. Granule swizzle
// g' = g ^ ((row>>1)&3) applied on BOTH write and read (rule #21).
// Falsification: >=340 us or fail -> revert champion, declare plateau.
// ---------------------------------------------------------------------------

typedef __attribute__((ext_vector_type(8))) short short8;
typedef __attribute__((ext_vector_type(8))) unsigned short ushort8_t;
typedef __attribute__((ext_vector_type(4))) float f32x4;

__device__ __forceinline__ unsigned short f2bf(float f) {
    unsigned int u = __float_as_uint(f);
    u += 0x7fffu + ((u >> 16) & 1u);           // round-to-nearest-even
    return (unsigned short)(u >> 16);
}
__device__ __forceinline__ float bf2f(unsigned short h) {
    return __uint_as_float(((unsigned int)h) << 16);
}

__device__ __forceinline__ float waveMax(float v) {
    #pragma unroll
    for (int off = 32; off > 0; off >>= 1) v = fmaxf(v, __shfl_xor(v, off, 64));
    return v;
}
__device__ __forceinline__ float waveSum(float v) {
    #pragma unroll
    for (int off = 32; off > 0; off >>= 1) v += __shfl_xor(v, off, 64);
    return v;
}

// ---- Kernel A: q[b, col] = sum_m x[b, idx, m] * Wq[m, col] -----------------
__global__ void k_q(const float* __restrict__ x, const float* __restrict__ wq,
                    const int* __restrict__ idxp, float* __restrict__ qout, int sfull) {
    const int tid = threadIdx.x;
    const int col = blockIdx.x * 256 + tid;
    const int b   = blockIdx.y;
    const int idx = *idxp;
    const float* xr = x + ((size_t)b * sfull + idx) * MD;
    float a0 = 0.f, a1 = 0.f, a2 = 0.f, a3 = 0.f;
    for (int m = 0; m < MD; m += 4) {
        a0 += xr[m]     * wq[(size_t)m * MD + col];
        a1 += xr[m + 1] * wq[(size_t)(m + 1) * MD + col];
        a2 += xr[m + 2] * wq[(size_t)(m + 2) * MD + col];
        a3 += xr[m + 3] * wq[(size_t)(m + 3) * MD + col];
    }
    qout[(size_t)b * MD + col] = (a0 + a1) + (a2 + a3);
}

// ---- Kernel B: wtil[b,h,m] -------------------------------------------------
__global__ void k_wtil(const float* __restrict__ wk, const float* __restrict__ q,
                       float* __restrict__ wtil) {
    const int tid = threadIdx.x;
    const int h  = blockIdx.x;
    const int b0 = blockIdx.y * 2;
    for (int mi = 0; mi < 4; ++mi) {
        const int m = mi * 256 + tid;
        const float4* wrow = (const float4*)(wk + (size_t)m * MD + h * D_);
        float4 wv[16];
        #pragma unroll
        for (int j = 0; j < 16; ++j) wv[j] = wrow[j];
        #pragma unroll
        for (int bb = 0; bb < 2; ++bb) {
            const float* qh = q + (size_t)(b0 + bb) * MD + h * D_;
            float acc = 0.f;
            #pragma unroll
            for (int j = 0; j < 16; ++j)
                acc += wv[j].x * qh[4*j] + wv[j].y * qh[4*j+1]
                     + wv[j].z * qh[4*j+2] + wv[j].w * qh[4*j+3];
            wtil[((size_t)(b0 + bb) * H_ + h) * MD + m] = acc;
        }
    }
}

// ---- Kernel P1: scores via split-bf16 MFMA ---------------------------------
// grid (64 b, 8 s-tiles of 512), block 256 (4 waves). Wave owns 128 s-rows.
// 32 windows of 32 m-cols; per window: stage hi/lo bf16 (18 b128 writes),
// then 8 tiles x {mfma(Wh,Xh), mfma(Wl,Xh), mfma(Wh,Xl)}.
__global__ __launch_bounds__(256) void k_scores(
        const float* __restrict__ x, const float* __restrict__ wtil,
        const int* __restrict__ idxp, float* __restrict__ scores, int sfull) {
    // per-wave bf16 tiles, rows of 32 elems (64 B), granule = 8 bf16.
    __shared__ __align__(16) unsigned short Xh[4][128 * 32];
    __shared__ __align__(16) unsigned short Xl[4][128 * 32];
    __shared__ __align__(16) unsigned short Wh[4][16 * 32];
    __shared__ __align__(16) unsigned short Wl[4][16 * 32];

    const int tid   = threadIdx.x;
    const int w     = tid >> 6;
    const int lane  = tid & 63;
    const int hquad = lane >> 4;      // 0..3 : k-granule for frag reads
    const int hs    = lane & 15;      // A-row (h) / B-col (s) for frag reads
    const int b     = blockIdx.x;
    const int sblk  = blockIdx.y * 512;
    const int s0    = sblk + w * 128; // this wave's first s-row
    const int S     = *idxp + 1;
    if (sblk >= S) return;

    const float* xb = x    + (size_t)b * sfull * MD;
    const float* wb = wtil + (size_t)b * H_ * MD;

    unsigned short* XhW = Xh[w];
    unsigned short* XlW = Xl[w];
    unsigned short* WhW = Wh[w];
    unsigned short* WlW = Wl[w];

    const int csl = lane >> 2;        // 0..15 staging row within group of 16
    const int cf4 = lane & 3;         // 0..3  8-col granule within window
    const int swk = (csl >> 1) & 3;   // write-side swizzle key
    const int gW  = (cf4 ^ swk) * 8;  // swizzled granule offset (ushorts)

    // per-wave window-ring phase: decorrelate HBM channel usage
    const int phase = (b + blockIdx.y * 8 + w) & 31;
#define MCOF(T) ((((T) + phase) & 31) * 32)

    f32x4 acc[8];
    #pragma unroll
    for (int T = 0; T < 8; ++T) { acc[T][0]=0.f; acc[T][1]=0.f; acc[T][2]=0.f; acc[T][3]=0.f; }

    float4 nx[16];
    float4 nw0, nw1;

#define ISSUE(MC) do {                                                         \
        _Pragma("unroll")                                                      \
        for (int i = 0; i < 8; ++i) {                                          \
            int srow = s0 + i * 16 + csl;                                      \
            if (srow < S) {                                                    \
                nx[2*i]   = *(const float4*)(xb + (size_t)srow * MD + (MC) + cf4 * 8);     \
                nx[2*i+1] = *(const float4*)(xb + (size_t)srow * MD + (MC) + cf4 * 8 + 4); \
            } else {                                                           \
                nx[2*i]   = make_float4(0.f, 0.f, 0.f, 0.f);                   \
                nx[2*i+1] = make_float4(0.f, 0.f, 0.f, 0.f);                   \
            }                                                                  \
        }                                                                      \
        nw0 = *(const float4*)(wb + (size_t)csl * MD + (MC) + cf4 * 8);        \
        nw1 = *(const float4*)(wb + (size_t)csl * MD + (MC) + cf4 * 8 + 4);    \
    } while (0)

#define CVT8(A, B, HV, LV) do {                                                \
        (HV)[0]=f2bf((A).x); (LV)[0]=f2bf((A).x - bf2f((HV)[0]));              \
        (HV)[1]=f2bf((A).y); (LV)[1]=f2bf((A).y - bf2f((HV)[1]));              \
        (HV)[2]=f2bf((A).z); (LV)[2]=f2bf((A).z - bf2f((HV)[2]));              \
        (HV)[3]=f2bf((A).w); (LV)[3]=f2bf((A).w - bf2f((HV)[3]));              \
        (HV)[4]=f2bf((B).x); (LV)[4]=f2bf((B).x - bf2f((HV)[4]));              \
        (HV)[5]=f2bf((B).y); (LV)[5]=f2bf((B).y - bf2f((HV)[5]));              \
        (HV)[6]=f2bf((B).z); (LV)[6]=f2bf((B).z - bf2f((HV)[6]));              \
        (HV)[7]=f2bf((B).w); (LV)[7]=f2bf((B).w - bf2f((HV)[7]));              \
    } while (0)

#define COMMIT() do {                                                          \
        _Pragma("unroll")                                                      \
        for (int i = 0; i < 8; ++i) {                                          \
            ushort8_t hv, lv;                                                  \
            CVT8(nx[2*i], nx[2*i+1], hv, lv);                                  \
            const int off = (i * 16 + csl) * 32 + gW;                          \
            *(ushort8_t*)(&XhW[off]) = hv;                                     \
            *(ushort8_t*)(&XlW[off]) = lv;                                     \
        }                                                                      \
        {                                                                      \
            ushort8_t hv, lv;                                                  \
            CVT8(nw0, nw1, hv, lv);                                            \
            const int off = csl * 32 + gW;                                     \
            *(ushort8_t*)(&WhW[off]) = hv;                                     \
            *(ushort8_t*)(&WlW[off]) = lv;                                     \
        }                                                                      \
    } while (0)

    const int rkey  = (hs >> 1) & 3;                 // read-side swizzle key
    const int wgoff = hs * 32 + ((hquad ^ rkey) * 8);  // W frag offset (rows h)

    ISSUE(MCOF(0));

    for (int t = 0; t < 32; ++t) {
        COMMIT();                              // convert + stage window t
        if (t + 1 < 32) ISSUE(MCOF(t + 1));    // prefetch next window
        // MFMA: A = w-tilde [16h x 32k], B = x^T [32k x 16s] -> D[h][s]
        short8 wfh = *(const short8*)(&WhW[wgoff]);
        short8 wfl = *(const short8*)(&WlW[wgoff]);
        #pragma unroll
        for (int T = 0; T < 8; ++T) {
            const int xoff = (T * 16 + hs) * 32 + ((hquad ^ rkey) * 8);
            short8 xfh = *(const short8*)(&XhW[xoff]);
            acc[T] = __builtin_amdgcn_mfma_f32_16x16x32_bf16(wfh, xfh, acc[T], 0, 0, 0);
            acc[T] = __builtin_amdgcn_mfma_f32_16x16x32_bf16(wfl, xfh, acc[T], 0, 0, 0);
            short8 xfl = *(const short8*)(&XlW[xoff]);
            acc[T] = __builtin_amdgcn_mfma_f32_16x16x32_bf16(wfh, xfl, acc[T], 0, 0, 0);
        }
    }
#undef ISSUE
#undef COMMIT
#undef CVT8
#undef MCOF

    // D mapping (m89): col s = lane&15, row h = (lane>>4)*4 + reg
    #pragma unroll
    for (int T = 0; T < 8; ++T) {
        const int s = s0 + T * 16 + hs;
        if (s < S) {
            #pragma unroll
            for (int r = 0; r < 4; ++r) {
                const int h = hquad * 4 + r;
                scores[((size_t)b * H_ + h) * sfull + s] = acc[T][r] * 0.125f;
            }
        }
    }
}

// ---- Kernel C: softmax + sparse gather + Wv projection ---------------------
__global__ void k_attn(const float* __restrict__ x, const float* __restrict__ scores,
                       const float* __restrict__ wv, const int* __restrict__ idxp,
                       float* __restrict__ concat, int sfull) {
    __shared__ float red[8];
    __shared__ int   scanw[4];
    __shared__ int   lidx[4096];
    __shared__ float lw[4096];
    __shared__ float ylds[1024];
    __shared__ float pred[256];

    const int tid = threadIdx.x;
    const int h = blockIdx.x, b = blockIdx.y;
    const int S = *idxp + 1;
    const float* sc = scores + ((size_t)b * H_ + h) * sfull;

    float ls[16];
    float mx = -INFINITY;
    #pragma unroll
    for (int k = 0; k < 16; ++k) {
        int s = tid + 256 * k;
        if (s < S) { ls[k] = sc[s]; mx = fmaxf(mx, ls[k]); }
        else ls[k] = -INFINITY;
    }
    mx = waveMax(mx);
    const int wid = tid >> 6, lane = tid & 63;
    if (lane == 0) red[wid] = mx;
    __syncthreads();
    mx = fmaxf(fmaxf(red[0], red[1]), fmaxf(red[2], red[3]));

    float sum = 0.f; int cnt = 0;
    #pragma unroll
    for (int k = 0; k < 16; ++k) {
        if (ls[k] > -INFINITY) {
            float e = ls[k] - mx;
            sum += expf(e);
            if (e > -34.f) ++cnt;
        }
    }
    sum = waveSum(sum);
    __syncthreads();
    if (lane == 0) red[4 + wid] = sum;
    __syncthreads();
    const float inv = 1.f / (red[4] + red[5] + red[6] + red[7]);

    int inc = cnt;
    #pragma unroll
    for (int off = 1; off < 64; off <<= 1) {
        int t = __shfl_up(inc, off, 64);
        if (lane >= off) inc += t;
    }
    if (lane == 63) scanw[wid] = inc;
    __syncthreads();
    int wbase = 0, total = 0;
    #pragma unroll
    for (int ww = 0; ww < 4; ++ww) {
        int t = scanw[ww];
        if (ww < wid) wbase += t;
        total += t;
    }
    int pos = wbase + inc - cnt;
    #pragma unroll
    for (int k = 0; k < 16; ++k) {
        if (ls[k] > -INFINITY) {
            float e = ls[k] - mx;
            if (e > -34.f) { lidx[pos] = tid + 256 * k; lw[pos] = expf(e) * inv; ++pos; }
        }
    }
    __syncthreads();

    float4 acc = make_float4(0.f, 0.f, 0.f, 0.f);
    const float* xb = x + (size_t)b * sfull * MD;
    for (int e = 0; e < total; ++e) {
        int s = lidx[e]; float w = lw[e];
        float4 xv = *(const float4*)(xb + (size_t)s * MD + tid * 4);
        acc.x += w * xv.x; acc.y += w * xv.y; acc.z += w * xv.z; acc.w += w * xv.w;
    }
    *(float4*)(&ylds[tid * 4]) = acc;
    __syncthreads();

    const int d = tid & 63, g = tid >> 6;
    const float* wcol = wv + (size_t)h * D_ + d;
    float part = 0.f;
    for (int m = g * 256; m < g * 256 + 256; ++m)
        part += ylds[m] * wcol[(size_t)m * MD];
    pred[tid] = part;
    __syncthreads();
    if (tid < 64) {
        float v = pred[tid] + pred[tid + 64] + pred[tid + 128] + pred[tid + 192];
        concat[(size_t)b * MD + h * D_ + tid] = v;
    }
}

// ---- Kernel T: fcwt[m][n] = fcW[n][m] --------------------------------------
__global__ void k_transpose(const float* __restrict__ a, float* __restrict__ at) {
    __shared__ float t[32][33];
    const int bx = blockIdx.x * 32, by = blockIdx.y * 32;
    const int tx = threadIdx.x & 31, ty = threadIdx.x >> 5;
    for (int r = ty; r < 32; r += 8)
        t[r][tx] = a[(size_t)(by + r) * MD + bx + tx];
    __syncthreads();
    for (int r = ty; r < 32; r += 8)
        at[(size_t)(bx + r) * MD + by + tx] = t[tx][r];
}

// ---- Kernel D: integ = concat @ fcW^T + bias -------------------------------
__global__ void k_fc(const float* __restrict__ concat, const float* __restrict__ fcwt,
                     const float* __restrict__ bias, float* __restrict__ integ) {
    __shared__ float c[1024];
    __shared__ float pred[256];
    const int tid = threadIdx.x, b = blockIdx.x;
    const int n0 = blockIdx.y * 64;
    const int nl = tid & 63, mg = tid >> 6;
    #pragma unroll
    for (int k = 0; k < 4; ++k) c[tid + 256 * k] = concat[(size_t)b * MD + tid + 256 * k];
    __syncthreads();
    const int mbase = mg * 256;
    float a0 = 0.f, a1 = 0.f, a2 = 0.f, a3 = 0.f;
    for (int m = 0; m < 256; m += 4) {
        a0 += c[mbase + m]     * fcwt[(size_t)(mbase + m) * MD + n0 + nl];
        a1 += c[mbase + m + 1] * fcwt[(size_t)(mbase + m + 1) * MD + n0 + nl];
        a2 += c[mbase + m + 2] * fcwt[(size_t)(mbase + m + 2) * MD + n0 + nl];
        a3 += c[mbase + m + 3] * fcwt[(size_t)(mbase + m + 3) * MD + n0 + nl];
    }
    pred[tid] = (a0 + a1) + (a2 + a3);
    __syncthreads();
    if (tid < 64)
        integ[(size_t)b * MD + n0 + tid] =
            pred[tid] + pred[tid + 64] + pred[tid + 128] + pred[tid + 192] + bias[n0 + tid];
}

// ---- Kernel E: LayerNorm ---------------------------------------------------
__global__ void k_ln(const float* __restrict__ integ, const float* __restrict__ gamma,
                     const float* __restrict__ beta, float* __restrict__ out) {
    __shared__ float red[8];
    const int tid = threadIdx.x, b = blockIdx.x;
    float v[4];
    #pragma unroll
    for (int k = 0; k < 4; ++k) v[k] = integ[(size_t)b * MD + tid + 256 * k];
    float s = v[0] + v[1] + v[2] + v[3];
    s = waveSum(s);
    const int wid = tid >> 6, lane = tid & 63;
    if (lane == 0) red[wid] = s;
    __syncthreads();
    const float mean = (red[0] + red[1] + red[2] + red[3]) * (1.f / MD);
    float q = 0.f;
    #pragma unroll
    for (int k = 0; k < 4; ++k) { float d = v[k] - mean; q += d * d; }
    q = waveSum(q);
    __syncthreads();
    if (lane == 0) red[4 + wid] = q;
    __syncthreads();
    const float var = (red[4] + red[5] + red[6] + red[7]) * (1.f / MD);
    const float rs = rsqrtf(var + LNEPS);
    #pragma unroll
    for (int k = 0; k < 4; ++k) {
        int i = tid + 256 * k;
        out[(size_t)b * MD + i] = (v[k] - mean) * rs * gamma[i] + beta[i];
    }
}

extern "C" void kernel_launch(void* const* d_in, const int* in_sizes, int n_in,
                              void* d_out, int out_size, void* d_ws, size_t ws_size,
                              hipStream_t stream) {
    const float* x     = (const float*)d_in[0];
    const float* wq    = (const float*)d_in[1];
    const float* wk    = (const float*)d_in[2];
    const float* wvp   = (const float*)d_in[3];
    const float* fcw   = (const float*)d_in[4];
    const float* fcb   = (const float*)d_in[5];
    const float* gamma = (const float*)d_in[6];
    const float* beta  = (const float*)d_in[7];
    const int*   idxp  = (const int*)d_in[8];
    float* out = (float*)d_out;

    const int sfull = in_sizes[0] / (B_ * MD);   // 4096

    float* q      = (float*)d_ws;
    float* wtil   = q      + (size_t)B_ * MD;
    float* scores = wtil   + (size_t)B_ * H_ * MD;
    float* concat = scores + (size_t)B_ * H_ * sfull;
    float* integ  = concat + (size_t)B_ * MD;
    float* fcwt   = integ  + (size_t)B_ * MD;

    hipLaunchKernelGGL(k_q,         dim3(4, 64),           dim3(256), 0, stream, x, wq, idxp, q, sfull);
    hipLaunchKernelGGL(k_wtil,      dim3(16, 32),          dim3(256), 0, stream, wk, q, wtil);
    hipLaunchKernelGGL(k_scores,    dim3(B_, (sfull + 511) / 512), dim3(256), 0, stream, x, wtil, idxp, scores, sfull);
    hipLaunchKernelGGL(k_transpose, dim3(32, 32),          dim3(256), 0, stream, fcw, fcwt);
    hipLaunchKernelGGL(k_attn,      dim3(H_, B_),          dim3(256), 0, stream, x, scores, wvp, idxp, concat, sfull);
    hipLaunchKernelGGL(k_fc,        dim3(64, 16),          dim3(256), 0, stream, concat, fcwt, fcb, integ);
    hipLaunchKernelGGL(k_ln,        dim3(B_),              dim3(256), 0, stream, integ, gamma, beta, out);
}

// Round 19
// 301.443 us; speedup vs baseline: 1.2438x; 1.0121x over previous
//
#include <hip/hip_runtime.h>
#include <hip/hip_bf16.h>
#include <math.h>

#define B_   64
#define MD   1024
#define H_   16
#define D_   64
#define LNEPS 1e-5f

// ---------------------------------------------------------------------------
// v18 = v17 (split-bf16 MFMA k_scores, 305 us) with NATIVE bf16 conversions:
// hand-rolled RNE bit-twiddling (9 VALU ops/elem, blocks cvt_pk fusion)
// -> __float2bfloat16 casts (~2.5 ops/elem, compiler emits v_cvt_pk_bf16_f32
// per m240). Conversion was the largest non-HBM term (~61 us chip-wide).
//
// k_scores: scores = (xh+xl)·(wh+wl) via 3x mfma_f32_16x16x32_bf16 (drop
// xl·wl; bf16 products exact in fp32 acc; absmax identical to fp32 champion).
// Per 32-col window/wave: 18 b128 LDS writes + 18 frag reads + 24 MFMA.
// D[h][s] mapping (m89): s = lane&15, h = (lane>>4)*4 + reg.
// Granule swizzle g' = g ^ ((row>>1)&3) on both write and read (rule #21).
// ---------------------------------------------------------------------------

typedef __attribute__((ext_vector_type(8))) short short8;
typedef __attribute__((ext_vector_type(8))) unsigned short ushort8_t;
typedef __attribute__((ext_vector_type(4))) float f32x4;

__device__ __forceinline__ unsigned short f2bf(float f) {
    __hip_bfloat16 h = __float2bfloat16(f);     // native cvt (RNE); pk-fusable
    unsigned short u;
    __builtin_memcpy(&u, &h, 2);
    return u;
}
__device__ __forceinline__ float bf2f(unsigned short h) {
    return __uint_as_float(((unsigned int)h) << 16);
}

__device__ __forceinline__ float waveMax(float v) {
    #pragma unroll
    for (int off = 32; off > 0; off >>= 1) v = fmaxf(v, __shfl_xor(v, off, 64));
    return v;
}
__device__ __forceinline__ float waveSum(float v) {
    #pragma unroll
    for (int off = 32; off > 0; off >>= 1) v += __shfl_xor(v, off, 64);
    return v;
}

// ---- Kernel A: q[b, col] = sum_m x[b, idx, m] * Wq[m, col] -----------------
__global__ void k_q(const float* __restrict__ x, const float* __restrict__ wq,
                    const int* __restrict__ idxp, float* __restrict__ qout, int sfull) {
    const int tid = threadIdx.x;
    const int col = blockIdx.x * 256 + tid;
    const int b   = blockIdx.y;
    const int idx = *idxp;
    const float* xr = x + ((size_t)b * sfull + idx) * MD;
    float a0 = 0.f, a1 = 0.f, a2 = 0.f, a3 = 0.f;
    for (int m = 0; m < MD; m += 4) {
        a0 += xr[m]     * wq[(size_t)m * MD + col];
        a1 += xr[m + 1] * wq[(size_t)(m + 1) * MD + col];
        a2 += xr[m + 2] * wq[(size_t)(m + 2) * MD + col];
        a3 += xr[m + 3] * wq[(size_t)(m + 3) * MD + col];
    }
    qout[(size_t)b * MD + col] = (a0 + a1) + (a2 + a3);
}

// ---- Kernel B: wtil[b,h,m] -------------------------------------------------
__global__ void k_wtil(const float* __restrict__ wk, const float* __restrict__ q,
                       float* __restrict__ wtil) {
    const int tid = threadIdx.x;
    const int h  = blockIdx.x;
    const int b0 = blockIdx.y * 2;
    for (int mi = 0; mi < 4; ++mi) {
        const int m = mi * 256 + tid;
        const float4* wrow = (const float4*)(wk + (size_t)m * MD + h * D_);
        float4 wv[16];
        #pragma unroll
        for (int j = 0; j < 16; ++j) wv[j] = wrow[j];
        #pragma unroll
        for (int bb = 0; bb < 2; ++bb) {
            const float* qh = q + (size_t)(b0 + bb) * MD + h * D_;
            float acc = 0.f;
            #pragma unroll
            for (int j = 0; j < 16; ++j)
                acc += wv[j].x * qh[4*j] + wv[j].y * qh[4*j+1]
                     + wv[j].z * qh[4*j+2] + wv[j].w * qh[4*j+3];
            wtil[((size_t)(b0 + bb) * H_ + h) * MD + m] = acc;
        }
    }
}

// ---- Kernel P1: scores via split-bf16 MFMA ---------------------------------
// grid (64 b, 8 s-tiles of 512), block 256 (4 waves). Wave owns 128 s-rows.
__global__ __launch_bounds__(256) void k_scores(
        const float* __restrict__ x, const float* __restrict__ wtil,
        const int* __restrict__ idxp, float* __restrict__ scores, int sfull) {
    __shared__ __align__(16) unsigned short Xh[4][128 * 32];
    __shared__ __align__(16) unsigned short Xl[4][128 * 32];
    __shared__ __align__(16) unsigned short Wh[4][16 * 32];
    __shared__ __align__(16) unsigned short Wl[4][16 * 32];

    const int tid   = threadIdx.x;
    const int w     = tid >> 6;
    const int lane  = tid & 63;
    const int hquad = lane >> 4;      // 0..3 : k-granule for frag reads
    const int hs    = lane & 15;      // A-row (h) / B-col (s) for frag reads
    const int b     = blockIdx.x;
    const int sblk  = blockIdx.y * 512;
    const int s0    = sblk + w * 128; // this wave's first s-row
    const int S     = *idxp + 1;
    if (sblk >= S) return;

    const float* xb = x    + (size_t)b * sfull * MD;
    const float* wb = wtil + (size_t)b * H_ * MD;

    unsigned short* XhW = Xh[w];
    unsigned short* XlW = Xl[w];
    unsigned short* WhW = Wh[w];
    unsigned short* WlW = Wl[w];

    const int csl = lane >> 2;        // 0..15 staging row within group of 16
    const int cf4 = lane & 3;         // 0..3  8-col granule within window
    const int swk = (csl >> 1) & 3;   // write-side swizzle key
    const int gW  = (cf4 ^ swk) * 8;  // swizzled granule offset (ushorts)

    // per-wave window-ring phase: decorrelate HBM channel usage
    const int phase = (b + blockIdx.y * 8 + w) & 31;
#define MCOF(T) ((((T) + phase) & 31) * 32)

    f32x4 acc[8];
    #pragma unroll
    for (int T = 0; T < 8; ++T) { acc[T][0]=0.f; acc[T][1]=0.f; acc[T][2]=0.f; acc[T][3]=0.f; }

    float4 nx[16];
    float4 nw0, nw1;

#define ISSUE(MC) do {                                                         \
        _Pragma("unroll")                                                      \
        for (int i = 0; i < 8; ++i) {                                          \
            int srow = s0 + i * 16 + csl;                                      \
            if (srow < S) {                                                    \
                nx[2*i]   = *(const float4*)(xb + (size_t)srow * MD + (MC) + cf4 * 8);     \
                nx[2*i+1] = *(const float4*)(xb + (size_t)srow * MD + (MC) + cf4 * 8 + 4); \
            } else {                                                           \
                nx[2*i]   = make_float4(0.f, 0.f, 0.f, 0.f);                   \
                nx[2*i+1] = make_float4(0.f, 0.f, 0.f, 0.f);                   \
            }                                                                  \
        }                                                                      \
        nw0 = *(const float4*)(wb + (size_t)csl * MD + (MC) + cf4 * 8);        \
        nw1 = *(const float4*)(wb + (size_t)csl * MD + (MC) + cf4 * 8 + 4);    \
    } while (0)

#define CVT8(A, B, HV, LV) do {                                                \
        (HV)[0]=f2bf((A).x); (LV)[0]=f2bf((A).x - bf2f((HV)[0]));              \
        (HV)[1]=f2bf((A).y); (LV)[1]=f2bf((A).y - bf2f((HV)[1]));              \
        (HV)[2]=f2bf((A).z); (LV)[2]=f2bf((A).z - bf2f((HV)[2]));              \
        (HV)[3]=f2bf((A).w); (LV)[3]=f2bf((A).w - bf2f((HV)[3]));              \
        (HV)[4]=f2bf((B).x); (LV)[4]=f2bf((B).x - bf2f((HV)[4]));              \
        (HV)[5]=f2bf((B).y); (LV)[5]=f2bf((B).y - bf2f((HV)[5]));              \
        (HV)[6]=f2bf((B).z); (LV)[6]=f2bf((B).z - bf2f((HV)[6]));              \
        (HV)[7]=f2bf((B).w); (LV)[7]=f2bf((B).w - bf2f((HV)[7]));              \
    } while (0)

#define COMMIT() do {                                                          \
        _Pragma("unroll")                                                      \
        for (int i = 0; i < 8; ++i) {                                          \
            ushort8_t hv, lv;                                                  \
            CVT8(nx[2*i], nx[2*i+1], hv, lv);                                  \
            const int off = (i * 16 + csl) * 32 + gW;                          \
            *(ushort8_t*)(&XhW[off]) = hv;                                     \
            *(ushort8_t*)(&XlW[off]) = lv;                                     \
        }                                                                      \
        {                                                                      \
            ushort8_t hv, lv;                                                  \
            CVT8(nw0, nw1, hv, lv);                                            \
            const int off = csl * 32 + gW;                                     \
            *(ushort8_t*)(&WhW[off]) = hv;                                     \
            *(ushort8_t*)(&WlW[off]) = lv;                                     \
        }                                                                      \
    } while (0)

    const int rkey  = (hs >> 1) & 3;                   // read-side swizzle key
    const int wgoff = hs * 32 + ((hquad ^ rkey) * 8);  // W frag offset (rows h)

    ISSUE(MCOF(0));

    for (int t = 0; t < 32; ++t) {
        COMMIT();                              // convert + stage window t
        if (t + 1 < 32) ISSUE(MCOF(t + 1));    // prefetch next window
        // MFMA: A = w-tilde [16h x 32k], B = x^T [32k x 16s] -> D[h][s]
        short8 wfh = *(const short8*)(&WhW[wgoff]);
        short8 wfl = *(const short8*)(&WlW[wgoff]);
        #pragma unroll
        for (int T = 0; T < 8; ++T) {
            const int xoff = (T * 16 + hs) * 32 + ((hquad ^ rkey) * 8);
            short8 xfh = *(const short8*)(&XhW[xoff]);
            acc[T] = __builtin_amdgcn_mfma_f32_16x16x32_bf16(wfh, xfh, acc[T], 0, 0, 0);
            acc[T] = __builtin_amdgcn_mfma_f32_16x16x32_bf16(wfl, xfh, acc[T], 0, 0, 0);
            short8 xfl = *(const short8*)(&XlW[xoff]);
            acc[T] = __builtin_amdgcn_mfma_f32_16x16x32_bf16(wfh, xfl, acc[T], 0, 0, 0);
        }
    }
#undef ISSUE
#undef COMMIT
#undef CVT8
#undef MCOF

    // D mapping (m89): col s = lane&15, row h = (lane>>4)*4 + reg
    #pragma unroll
    for (int T = 0; T < 8; ++T) {
        const int s = s0 + T * 16 + hs;
        if (s < S) {
            #pragma unroll
            for (int r = 0; r < 4; ++r) {
                const int h = hquad * 4 + r;
                scores[((size_t)b * H_ + h) * sfull + s] = acc[T][r] * 0.125f;
            }
        }
    }
}

// ---- Kernel C: softmax + sparse gather + Wv projection ---------------------
__global__ void k_attn(const float* __restrict__ x, const float* __restrict__ scores,
                       const float* __restrict__ wv, const int* __restrict__ idxp,
                       float* __restrict__ concat, int sfull) {
    __shared__ float red[8];
    __shared__ int   scanw[4];
    __shared__ int   lidx[4096];
    __shared__ float lw[4096];
    __shared__ float ylds[1024];
    __shared__ float pred[256];

    const int tid = threadIdx.x;
    const int h = blockIdx.x, b = blockIdx.y;
    const int S = *idxp + 1;
    const float* sc = scores + ((size_t)b * H_ + h) * sfull;

    float ls[16];
    float mx = -INFINITY;
    #pragma unroll
    for (int k = 0; k < 16; ++k) {
        int s = tid + 256 * k;
        if (s < S) { ls[k] = sc[s]; mx = fmaxf(mx, ls[k]); }
        else ls[k] = -INFINITY;
    }
    mx = waveMax(mx);
    const int wid = tid >> 6, lane = tid & 63;
    if (lane == 0) red[wid] = mx;
    __syncthreads();
    mx = fmaxf(fmaxf(red[0], red[1]), fmaxf(red[2], red[3]));

    float sum = 0.f; int cnt = 0;
    #pragma unroll
    for (int k = 0; k < 16; ++k) {
        if (ls[k] > -INFINITY) {
            float e = ls[k] - mx;
            sum += expf(e);
            if (e > -34.f) ++cnt;
        }
    }
    sum = waveSum(sum);
    __syncthreads();
    if (lane == 0) red[4 + wid] = sum;
    __syncthreads();
    const float inv = 1.f / (red[4] + red[5] + red[6] + red[7]);

    int inc = cnt;
    #pragma unroll
    for (int off = 1; off < 64; off <<= 1) {
        int t = __shfl_up(inc, off, 64);
        if (lane >= off) inc += t;
    }
    if (lane == 63) scanw[wid] = inc;
    __syncthreads();
    int wbase = 0, total = 0;
    #pragma unroll
    for (int ww = 0; ww < 4; ++ww) {
        int t = scanw[ww];
        if (ww < wid) wbase += t;
        total += t;
    }
    int pos = wbase + inc - cnt;
    #pragma unroll
    for (int k = 0; k < 16; ++k) {
        if (ls[k] > -INFINITY) {
            float e = ls[k] - mx;
            if (e > -34.f) { lidx[pos] = tid + 256 * k; lw[pos] = expf(e) * inv; ++pos; }
        }
    }
    __syncthreads();

    float4 acc = make_float4(0.f, 0.f, 0.f, 0.f);
    const float* xb = x + (size_t)b * sfull * MD;
    for (int e = 0; e < total; ++e) {
        int s = lidx[e]; float w = lw[e];
        float4 xv = *(const float4*)(xb + (size_t)s * MD + tid * 4);
        acc.x += w * xv.x; acc.y += w * xv.y; acc.z += w * xv.z; acc.w += w * xv.w;
    }
    *(float4*)(&ylds[tid * 4]) = acc;
    __syncthreads();

    const int d = tid & 63, g = tid >> 6;
    const float* wcol = wv + (size_t)h * D_ + d;
    float part = 0.f;
    for (int m = g * 256; m < g * 256 + 256; ++m)
        part += ylds[m] * wcol[(size_t)m * MD];
    pred[tid] = part;
    __syncthreads();
    if (tid < 64) {
        float v = pred[tid] + pred[tid + 64] + pred[tid + 128] + pred[tid + 192];
        concat[(size_t)b * MD + h * D_ + tid] = v;
    }
}

// ---- Kernel T: fcwt[m][n] = fcW[n][m] --------------------------------------
__global__ void k_transpose(const float* __restrict__ a, float* __restrict__ at) {
    __shared__ float t[32][33];
    const int bx = blockIdx.x * 32, by = blockIdx.y * 32;
    const int tx = threadIdx.x & 31, ty = threadIdx.x >> 5;
    for (int r = ty; r < 32; r += 8)
        t[r][tx] = a[(size_t)(by + r) * MD + bx + tx];
    __syncthreads();
    for (int r = ty; r < 32; r += 8)
        at[(size_t)(bx + r) * MD + by + tx] = t[tx][r];
}

// ---- Kernel D: integ = concat @ fcW^T + bias -------------------------------
__global__ void k_fc(const float* __restrict__ concat, const float* __restrict__ fcwt,
                     const float* __restrict__ bias, float* __restrict__ integ) {
    __shared__ float c[1024];
    __shared__ float pred[256];
    const int tid = threadIdx.x, b = blockIdx.x;
    const int n0 = blockIdx.y * 64;
    const int nl = tid & 63, mg = tid >> 6;
    #pragma unroll
    for (int k = 0; k < 4; ++k) c[tid + 256 * k] = concat[(size_t)b * MD + tid + 256 * k];
    __syncthreads();
    const int mbase = mg * 256;
    float a0 = 0.f, a1 = 0.f, a2 = 0.f, a3 = 0.f;
    for (int m = 0; m < 256; m += 4) {
        a0 += c[mbase + m]     * fcwt[(size_t)(mbase + m) * MD + n0 + nl];
        a1 += c[mbase + m + 1] * fcwt[(size_t)(mbase + m + 1) * MD + n0 + nl];
        a2 += c[mbase + m + 2] * fcwt[(size_t)(mbase + m + 2) * MD + n0 + nl];
        a3 += c[mbase + m + 3] * fcwt[(size_t)(mbase + m + 3) * MD + n0 + nl];
    }
    pred[tid] = (a0 + a1) + (a2 + a3);
    __syncthreads();
    if (tid < 64)
        integ[(size_t)b * MD + n0 + tid] =
            pred[tid] + pred[tid + 64] + pred[tid + 128] + pred[tid + 192] + bias[n0 + tid];
}

// ---- Kernel E: LayerNorm ---------------------------------------------------
__global__ void k_ln(const float* __restrict__ integ, const float* __restrict__ gamma,
                     const float* __restrict__ beta, float* __restrict__ out) {
    __shared__ float red[8];
    const int tid = threadIdx.x, b = blockIdx.x;
    float v[4];
    #pragma unroll
    for (int k = 0; k < 4; ++k) v[k] = integ[(size_t)b * MD + tid + 256 * k];
    float s = v[0] + v[1] + v[2] + v[3];
    s = waveSum(s);
    const int wid = tid >> 6, lane = tid & 63;
    if (lane == 0) red[wid] = s;
    __syncthreads();
    const float mean = (red[0] + red[1] + red[2] + red[3]) * (1.f / MD);
    float q = 0.f;
    #pragma unroll
    for (int k = 0; k < 4; ++k) { float d = v[k] - mean; q += d * d; }
    q = waveSum(q);
    __syncthreads();
    if (lane == 0) red[4 + wid] = q;
    __syncthreads();
    const float var = (red[4] + red[5] + red[6] + red[7]) * (1.f / MD);
    const float rs = rsqrtf(var + LNEPS);
    #pragma unroll
    for (int k = 0; k < 4; ++k) {
        int i = tid + 256 * k;
        out[(size_t)b * MD + i] = (v[k] - mean) * rs * gamma[i] + beta[i];
    }
}

extern "C" void kernel_launch(void* const* d_in, const int* in_sizes, int n_in,
                              void* d_out, int out_size, void* d_ws, size_t ws_size,
                              hipStream_t stream) {
    const float* x     = (const float*)d_in[0];
    const float* wq    = (const float*)d_in[1];
    const float* wk    = (const float*)d_in[2];
    const float* wvp   = (const float*)d_in[3];
    const float* fcw   = (const float*)d_in[4];
    const float* fcb   = (const float*)d_in[5];
    const float* gamma = (const float*)d_in[6];
    const float* beta  = (const float*)d_in[7];
    const int*   idxp  = (const int*)d_in[8];
    float* out = (float*)d_out;

    const int sfull = in_sizes[0] / (B_ * MD);   // 4096

    float* q      = (float*)d_ws;
    float* wtil   = q      + (size_t)B_ * MD;
    float* scores = wtil   + (size_t)B_ * H_ * MD;
    float* concat = scores + (size_t)B_ * H_ * sfull;
    float* integ  = concat + (size_t)B_ * MD;
    float* fcwt   = integ  + (size_t)B_ * MD;

    hipLaunchKernelGGL(k_q,         dim3(4, 64),           dim3(256), 0, stream, x, wq, idxp, q, sfull);
    hipLaunchKernelGGL(k_wtil,      dim3(16, 32),          dim3(256), 0, stream, wk, q, wtil);
    hipLaunchKernelGGL(k_scores,    dim3(B_, (sfull + 511) / 512), dim3(256), 0, stream, x, wtil, idxp, scores, sfull);
    hipLaunchKernelGGL(k_transpose, dim3(32, 32),          dim3(256), 0, stream, fcw, fcwt);
    hipLaunchKernelGGL(k_attn,      dim3(H_, B_),          dim3(256), 0, stream, x, scores, wvp, idxp, concat, sfull);
    hipLaunchKernelGGL(k_fc,        dim3(64, 16),          dim3(256), 0, stream, concat, fcwt, fcb, integ);
    hipLaunchKernelGGL(k_ln,        dim3(B_),              dim3(256), 0, stream, integ, gamma, beta, out);
}

// Round 20
// 293.200 us; speedup vs baseline: 1.2788x; 1.0281x over previous
//
#include <hip/hip_runtime.h>
#include <hip/hip_bf16.h>
#include <math.h>

#define B_   64
#define MD   1024
#define H_   16
#define D_   64
#define LNEPS 1e-5f

// ---------------------------------------------------------------------------
// v19 = v18 with ZERO-LDS k_scores: MFMA fragments loaded DIRECTLY from
// global memory (per-lane 32-B slices; wave covers 16 rows x 128 B = 16
// fully-consumed lines -> coalesced) and converted to split-bf16 in
// registers. The MFMA fragment layout IS the s<->m transpose, so the LDS
// staging that bound every fp32 variant (R4-R16) and still cost ~44 b128
// ops/window in v17/v18 is gone entirely. Unlike R12's zero-LDS failure:
// per-lane addresses (no scalar-load fantasy), acc = 16 VGPR, no spill.
// scores = (xh+xl)(wh+wl) via 3x mfma_f32_16x16x32_bf16 (drop xl*wl).
// Wave owns 64 rows (4 tiles of 16x16); grid (64 b, 16 sy) -> 16 waves/CU.
// Fragment layout (m89-consistent, validated by v17/v18 absmax == fp32):
// lane l: row/col = l&15, k-slice = (l>>4)*8..+8 contiguous.
// ---------------------------------------------------------------------------

typedef __attribute__((ext_vector_type(8))) short short8;
typedef __attribute__((ext_vector_type(8))) unsigned short ushort8_t;
typedef __attribute__((ext_vector_type(4))) float f32x4;

__device__ __forceinline__ unsigned short f2bf(float f) {
    __hip_bfloat16 h = __float2bfloat16(f);     // native cvt (RNE); pk-fusable
    unsigned short u;
    __builtin_memcpy(&u, &h, 2);
    return u;
}
__device__ __forceinline__ float bf2f(unsigned short h) {
    return __uint_as_float(((unsigned int)h) << 16);
}

__device__ __forceinline__ float waveMax(float v) {
    #pragma unroll
    for (int off = 32; off > 0; off >>= 1) v = fmaxf(v, __shfl_xor(v, off, 64));
    return v;
}
__device__ __forceinline__ float waveSum(float v) {
    #pragma unroll
    for (int off = 32; off > 0; off >>= 1) v += __shfl_xor(v, off, 64);
    return v;
}

// ---- Kernel A: q[b, col] = sum_m x[b, idx, m] * Wq[m, col] -----------------
__global__ void k_q(const float* __restrict__ x, const float* __restrict__ wq,
                    const int* __restrict__ idxp, float* __restrict__ qout, int sfull) {
    const int tid = threadIdx.x;
    const int col = blockIdx.x * 256 + tid;
    const int b   = blockIdx.y;
    const int idx = *idxp;
    const float* xr = x + ((size_t)b * sfull + idx) * MD;
    float a0 = 0.f, a1 = 0.f, a2 = 0.f, a3 = 0.f;
    for (int m = 0; m < MD; m += 4) {
        a0 += xr[m]     * wq[(size_t)m * MD + col];
        a1 += xr[m + 1] * wq[(size_t)(m + 1) * MD + col];
        a2 += xr[m + 2] * wq[(size_t)(m + 2) * MD + col];
        a3 += xr[m + 3] * wq[(size_t)(m + 3) * MD + col];
    }
    qout[(size_t)b * MD + col] = (a0 + a1) + (a2 + a3);
}

// ---- Kernel B: wtil[b,h,m] -------------------------------------------------
__global__ void k_wtil(const float* __restrict__ wk, const float* __restrict__ q,
                       float* __restrict__ wtil) {
    const int tid = threadIdx.x;
    const int h  = blockIdx.x;
    const int b0 = blockIdx.y * 2;
    for (int mi = 0; mi < 4; ++mi) {
        const int m = mi * 256 + tid;
        const float4* wrow = (const float4*)(wk + (size_t)m * MD + h * D_);
        float4 wv[16];
        #pragma unroll
        for (int j = 0; j < 16; ++j) wv[j] = wrow[j];
        #pragma unroll
        for (int bb = 0; bb < 2; ++bb) {
            const float* qh = q + (size_t)(b0 + bb) * MD + h * D_;
            float acc = 0.f;
            #pragma unroll
            for (int j = 0; j < 16; ++j)
                acc += wv[j].x * qh[4*j] + wv[j].y * qh[4*j+1]
                     + wv[j].z * qh[4*j+2] + wv[j].w * qh[4*j+3];
            wtil[((size_t)(b0 + bb) * H_ + h) * MD + m] = acc;
        }
    }
}

// ---- Kernel P1: scores via split-bf16 MFMA, zero LDS -----------------------
// grid (64 b, 16 s-tiles of 256), block 256 (4 waves). Wave owns 64 s-rows.
__global__ __launch_bounds__(256) void k_scores(
        const float* __restrict__ x, const float* __restrict__ wtil,
        const int* __restrict__ idxp, float* __restrict__ scores, int sfull) {
    const int tid   = threadIdx.x;
    const int w     = tid >> 6;
    const int lane  = tid & 63;
    const int hquad = lane >> 4;      // k-granule: elems hquad*8..+8
    const int hs    = lane & 15;      // A-row (h) / B-col (s)
    const int b     = blockIdx.x;
    const int sblk  = blockIdx.y * 256;
    const int s0    = sblk + w * 64;  // this wave's first s-row
    const int S     = *idxp + 1;
    if (sblk >= S) return;

    const float* xb = x    + (size_t)b * sfull * MD;
    const float* wb = wtil + (size_t)b * H_ * MD;

    // per-lane fragment row pointers (chunk-invariant part)
    const float* wrow = wb + (size_t)hs * MD + hquad * 8;
    const float* xrow0;
    const float* xrow1;
    const float* xrow2;
    const float* xrow3;
    {
        int r0 = s0 + 0 * 16 + hs; if (r0 >= S) r0 = S - 1;
        int r1 = s0 + 1 * 16 + hs; if (r1 >= S) r1 = S - 1;
        int r2 = s0 + 2 * 16 + hs; if (r2 >= S) r2 = S - 1;
        int r3 = s0 + 3 * 16 + hs; if (r3 >= S) r3 = S - 1;
        xrow0 = xb + (size_t)r0 * MD + hquad * 8;
        xrow1 = xb + (size_t)r1 * MD + hquad * 8;
        xrow2 = xb + (size_t)r2 * MD + hquad * 8;
        xrow3 = xb + (size_t)r3 * MD + hquad * 8;
    }

    // per-wave window-ring phase: decorrelate HBM channel usage
    const int phase = (b + blockIdx.y * 8 + w) & 31;
#define MCOF(T) ((((T) + phase) & 31) * 32)

    f32x4 acc0 = {0.f,0.f,0.f,0.f}, acc1 = {0.f,0.f,0.f,0.f};
    f32x4 acc2 = {0.f,0.f,0.f,0.f}, acc3 = {0.f,0.f,0.f,0.f};

    // convert 8 floats (2 x float4) -> hi/lo bf16 fragments
#define CVT(A, B, HV, LV) do {                                                 \
        (HV)[0]=(short)f2bf((A).x); (LV)[0]=(short)f2bf((A).x - bf2f((HV)[0])); \
        (HV)[1]=(short)f2bf((A).y); (LV)[1]=(short)f2bf((A).y - bf2f((HV)[1])); \
        (HV)[2]=(short)f2bf((A).z); (LV)[2]=(short)f2bf((A).z - bf2f((HV)[2])); \
        (HV)[3]=(short)f2bf((A).w); (LV)[3]=(short)f2bf((A).w - bf2f((HV)[3])); \
        (HV)[4]=(short)f2bf((B).x); (LV)[4]=(short)f2bf((B).x - bf2f((HV)[4])); \
        (HV)[5]=(short)f2bf((B).y); (LV)[5]=(short)f2bf((B).y - bf2f((HV)[5])); \
        (HV)[6]=(short)f2bf((B).z); (LV)[6]=(short)f2bf((B).z - bf2f((HV)[6])); \
        (HV)[7]=(short)f2bf((B).w); (LV)[7]=(short)f2bf((B).w - bf2f((HV)[7])); \
    } while (0)

#define TILE(XR, ACC) do {                                                     \
        float4 xa = *(const float4*)((XR) + mc);                               \
        float4 xc = *(const float4*)((XR) + mc + 4);                           \
        short8 xfh, xfl;                                                       \
        CVT(xa, xc, xfh, xfl);                                                 \
        ACC = __builtin_amdgcn_mfma_f32_16x16x32_bf16(wfh, xfh, ACC, 0, 0, 0); \
        ACC = __builtin_amdgcn_mfma_f32_16x16x32_bf16(wfl, xfh, ACC, 0, 0, 0); \
        ACC = __builtin_amdgcn_mfma_f32_16x16x32_bf16(wfh, xfl, ACC, 0, 0, 0); \
    } while (0)

    for (int t = 0; t < 32; ++t) {
        const int mc = MCOF(t);
        float4 wa = *(const float4*)(wrow + mc);
        float4 wc = *(const float4*)(wrow + mc + 4);
        short8 wfh, wfl;
        CVT(wa, wc, wfh, wfl);
        TILE(xrow0, acc0);
        TILE(xrow1, acc1);
        TILE(xrow2, acc2);
        TILE(xrow3, acc3);
    }
#undef TILE
#undef CVT
#undef MCOF

    // D mapping (m89): col s = lane&15, row h = (lane>>4)*4 + reg
#define STORE(ACC, T) do {                                                     \
        const int s = s0 + (T) * 16 + hs;                                      \
        if (s < S) {                                                           \
            _Pragma("unroll")                                                  \
            for (int r = 0; r < 4; ++r) {                                      \
                const int h = hquad * 4 + r;                                   \
                scores[((size_t)b * H_ + h) * sfull + s] = (ACC)[r] * 0.125f;  \
            }                                                                  \
        }                                                                      \
    } while (0)
    STORE(acc0, 0);
    STORE(acc1, 1);
    STORE(acc2, 2);
    STORE(acc3, 3);
#undef STORE
}

// ---- Kernel C: softmax + sparse gather + Wv projection ---------------------
__global__ void k_attn(const float* __restrict__ x, const float* __restrict__ scores,
                       const float* __restrict__ wv, const int* __restrict__ idxp,
                       float* __restrict__ concat, int sfull) {
    __shared__ float red[8];
    __shared__ int   scanw[4];
    __shared__ int   lidx[4096];
    __shared__ float lw[4096];
    __shared__ float ylds[1024];
    __shared__ float pred[256];

    const int tid = threadIdx.x;
    const int h = blockIdx.x, b = blockIdx.y;
    const int S = *idxp + 1;
    const float* sc = scores + ((size_t)b * H_ + h) * sfull;

    float ls[16];
    float mx = -INFINITY;
    #pragma unroll
    for (int k = 0; k < 16; ++k) {
        int s = tid + 256 * k;
        if (s < S) { ls[k] = sc[s]; mx = fmaxf(mx, ls[k]); }
        else ls[k] = -INFINITY;
    }
    mx = waveMax(mx);
    const int wid = tid >> 6, lane = tid & 63;
    if (lane == 0) red[wid] = mx;
    __syncthreads();
    mx = fmaxf(fmaxf(red[0], red[1]), fmaxf(red[2], red[3]));

    float sum = 0.f; int cnt = 0;
    #pragma unroll
    for (int k = 0; k < 16; ++k) {
        if (ls[k] > -INFINITY) {
            float e = ls[k] - mx;
            sum += expf(e);
            if (e > -34.f) ++cnt;
        }
    }
    sum = waveSum(sum);
    __syncthreads();
    if (lane == 0) red[4 + wid] = sum;
    __syncthreads();
    const float inv = 1.f / (red[4] + red[5] + red[6] + red[7]);

    int inc = cnt;
    #pragma unroll
    for (int off = 1; off < 64; off <<= 1) {
        int t = __shfl_up(inc, off, 64);
        if (lane >= off) inc += t;
    }
    if (lane == 63) scanw[wid] = inc;
    __syncthreads();
    int wbase = 0, total = 0;
    #pragma unroll
    for (int ww = 0; ww < 4; ++ww) {
        int t = scanw[ww];
        if (ww < wid) wbase += t;
        total += t;
    }
    int pos = wbase + inc - cnt;
    #pragma unroll
    for (int k = 0; k < 16; ++k) {
        if (ls[k] > -INFINITY) {
            float e = ls[k] - mx;
            if (e > -34.f) { lidx[pos] = tid + 256 * k; lw[pos] = expf(e) * inv; ++pos; }
        }
    }
    __syncthreads();

    float4 acc = make_float4(0.f, 0.f, 0.f, 0.f);
    const float* xb = x + (size_t)b * sfull * MD;
    for (int e = 0; e < total; ++e) {
        int s = lidx[e]; float w = lw[e];
        float4 xv = *(const float4*)(xb + (size_t)s * MD + tid * 4);
        acc.x += w * xv.x; acc.y += w * xv.y; acc.z += w * xv.z; acc.w += w * xv.w;
    }
    *(float4*)(&ylds[tid * 4]) = acc;
    __syncthreads();

    const int d = tid & 63, g = tid >> 6;
    const float* wcol = wv + (size_t)h * D_ + d;
    float part = 0.f;
    for (int m = g * 256; m < g * 256 + 256; ++m)
        part += ylds[m] * wcol[(size_t)m * MD];
    pred[tid] = part;
    __syncthreads();
    if (tid < 64) {
        float v = pred[tid] + pred[tid + 64] + pred[tid + 128] + pred[tid + 192];
        concat[(size_t)b * MD + h * D_ + tid] = v;
    }
}

// ---- Kernel T: fcwt[m][n] = fcW[n][m] --------------------------------------
__global__ void k_transpose(const float* __restrict__ a, float* __restrict__ at) {
    __shared__ float t[32][33];
    const int bx = blockIdx.x * 32, by = blockIdx.y * 32;
    const int tx = threadIdx.x & 31, ty = threadIdx.x >> 5;
    for (int r = ty; r < 32; r += 8)
        t[r][tx] = a[(size_t)(by + r) * MD + bx + tx];
    __syncthreads();
    for (int r = ty; r < 32; r += 8)
        at[(size_t)(bx + r) * MD + by + tx] = t[tx][r];
}

// ---- Kernel D: integ = concat @ fcW^T + bias -------------------------------
__global__ void k_fc(const float* __restrict__ concat, const float* __restrict__ fcwt,
                     const float* __restrict__ bias, float* __restrict__ integ) {
    __shared__ float c[1024];
    __shared__ float pred[256];
    const int tid = threadIdx.x, b = blockIdx.x;
    const int n0 = blockIdx.y * 64;
    const int nl = tid & 63, mg = tid >> 6;
    #pragma unroll
    for (int k = 0; k < 4; ++k) c[tid + 256 * k] = concat[(size_t)b * MD + tid + 256 * k];
    __syncthreads();
    const int mbase = mg * 256;
    float a0 = 0.f, a1 = 0.f, a2 = 0.f, a3 = 0.f;
    for (int m = 0; m < 256; m += 4) {
        a0 += c[mbase + m]     * fcwt[(size_t)(mbase + m) * MD + n0 + nl];
        a1 += c[mbase + m + 1] * fcwt[(size_t)(mbase + m + 1) * MD + n0 + nl];
        a2 += c[mbase + m + 2] * fcwt[(size_t)(mbase + m + 2) * MD + n0 + nl];
        a3 += c[mbase + m + 3] * fcwt[(size_t)(mbase + m + 3) * MD + n0 + nl];
    }
    pred[tid] = (a0 + a1) + (a2 + a3);
    __syncthreads();
    if (tid < 64)
        integ[(size_t)b * MD + n0 + tid] =
            pred[tid] + pred[tid + 64] + pred[tid + 128] + pred[tid + 192] + bias[n0 + tid];
}

// ---- Kernel E: LayerNorm ---------------------------------------------------
__global__ void k_ln(const float* __restrict__ integ, const float* __restrict__ gamma,
                     const float* __restrict__ beta, float* __restrict__ out) {
    __shared__ float red[8];
    const int tid = threadIdx.x, b = blockIdx.x;
    float v[4];
    #pragma unroll
    for (int k = 0; k < 4; ++k) v[k] = integ[(size_t)b * MD + tid + 256 * k];
    float s = v[0] + v[1] + v[2] + v[3];
    s = waveSum(s);
    const int wid = tid >> 6, lane = tid & 63;
    if (lane == 0) red[wid] = s;
    __syncthreads();
    const float mean = (red[0] + red[1] + red[2] + red[3]) * (1.f / MD);
    float q = 0.f;
    #pragma unroll
    for (int k = 0; k < 4; ++k) { float d = v[k] - mean; q += d * d; }
    q = waveSum(q);
    __syncthreads();
    if (lane == 0) red[4 + wid] = q;
    __syncthreads();
    const float var = (red[4] + red[5] + red[6] + red[7]) * (1.f / MD);
    const float rs = rsqrtf(var + LNEPS);
    #pragma unroll
    for (int k = 0; k < 4; ++k) {
        int i = tid + 256 * k;
        out[(size_t)b * MD + i] = (v[k] - mean) * rs * gamma[i] + beta[i];
    }
}

extern "C" void kernel_launch(void* const* d_in, const int* in_sizes, int n_in,
                              void* d_out, int out_size, void* d_ws, size_t ws_size,
                              hipStream_t stream) {
    const float* x     = (const float*)d_in[0];
    const float* wq    = (const float*)d_in[1];
    const float* wk    = (const float*)d_in[2];
    const float* wvp   = (const float*)d_in[3];
    const float* fcw   = (const float*)d_in[4];
    const float* fcb   = (const float*)d_in[5];
    const float* gamma = (const float*)d_in[6];
    const float* beta  = (const float*)d_in[7];
    const int*   idxp  = (const int*)d_in[8];
    float* out = (float*)d_out;

    const int sfull = in_sizes[0] / (B_ * MD);   // 4096

    float* q      = (float*)d_ws;
    float* wtil   = q      + (size_t)B_ * MD;
    float* scores = wtil   + (size_t)B_ * H_ * MD;
    float* concat = scores + (size_t)B_ * H_ * sfull;
    float* integ  = concat + (size_t)B_ * MD;
    float* fcwt   = integ  + (size_t)B_ * MD;

    hipLaunchKernelGGL(k_q,         dim3(4, 64),           dim3(256), 0, stream, x, wq, idxp, q, sfull);
    hipLaunchKernelGGL(k_wtil,      dim3(16, 32),          dim3(256), 0, stream, wk, q, wtil);
    hipLaunchKernelGGL(k_scores,    dim3(B_, (sfull + 255) / 256), dim3(256), 0, stream, x, wtil, idxp, scores, sfull);
    hipLaunchKernelGGL(k_transpose, dim3(32, 32),          dim3(256), 0, stream, fcw, fcwt);
    hipLaunchKernelGGL(k_attn,      dim3(H_, B_),          dim3(256), 0, stream, x, scores, wvp, idxp, concat, sfull);
    hipLaunchKernelGGL(k_fc,        dim3(64, 16),          dim3(256), 0, stream, concat, fcwt, fcb, integ);
    hipLaunchKernelGGL(k_ln,        dim3(B_),              dim3(256), 0, stream, integ, gamma, beta, out);
}